// Round 2
// baseline (1207.358 us; speedup 1.0000x reference)
//
#include <hip/hip_runtime.h>
#include <hip/hip_bf16.h>
#include <stdint.h>

// Attention_5265629905090: B=4, S=4096, D=256, fp32 in/out, int mask (1 = masked -> -1e9)
// Plan: proj (Q scaled 1/16 bf16, K bf16 row-major, V^T bf16) -> flash attn (split-KV x2) -> combine.

typedef __attribute__((ext_vector_type(8))) short bf16x8;
typedef __attribute__((ext_vector_type(4))) float f32x4;

__device__ __forceinline__ short f2bf(float f) {
    union { float f; uint32_t u; } v; v.f = f;
    uint32_t r = v.u + 0x7FFFu + ((v.u >> 16) & 1u);   // RNE
    return (short)(r >> 16);
}

// ---------------------------------------------------------------------------
// Projection GEMM: C[s][e] = sum_d X[s][d] * W[e][d]   (nn.Linear, y = x W^T)
// grid (128, 3), block 256.  proj: 0=Q (scaled 1/16), 1=K, 2=V^T
// ---------------------------------------------------------------------------
__global__ void proj_kernel(const float* __restrict__ encq,
                            const float* __restrict__ enck,
                            const float* __restrict__ encv,
                            const float* __restrict__ Wq,
                            const float* __restrict__ Wk,
                            const float* __restrict__ Wv,
                            short* __restrict__ q_out,   // [16384][256]
                            short* __restrict__ k_out,   // [16384][256]
                            short* __restrict__ vt_out)  // [4][256][4096]
{
    __shared__ short As[128][72];   // 72-short rows: 144B = 16B-aligned, bank-spread
    __shared__ short Bs[256][72];

    const int tid = threadIdx.x;
    const int wave = tid >> 6, lane = tid & 63, lo = lane & 15, hi = lane >> 4;
    const int proj = blockIdx.y;
    const int row0 = blockIdx.x * 128;

    const float* X = (proj == 0) ? encq : (proj == 1) ? enck : encv;
    const float* W = (proj == 0) ? Wq   : (proj == 1) ? Wk   : Wv;

    f32x4 acc[2][16];
    #pragma unroll
    for (int m = 0; m < 2; ++m)
        #pragma unroll
        for (int n = 0; n < 16; ++n) {
            f32x4 z = {0.f, 0.f, 0.f, 0.f};
            acc[m][n] = z;
        }

    for (int ks = 0; ks < 4; ++ks) {
        const int k0 = ks * 64;
        __syncthreads();
        // stage A tile: 128 rows x 64 cols fp32 -> bf16
        #pragma unroll
        for (int i = 0; i < 8; ++i) {
            int u = tid + i * 256;
            int r = u >> 4, c4 = u & 15;
            float4 v = *(const float4*)(X + (size_t)(row0 + r) * 256 + k0 + c4 * 4);
            short* dst = &As[r][c4 * 4];
            dst[0] = f2bf(v.x); dst[1] = f2bf(v.y); dst[2] = f2bf(v.z); dst[3] = f2bf(v.w);
        }
        // stage W tile: 256 rows x 64 cols
        #pragma unroll
        for (int i = 0; i < 16; ++i) {
            int u = tid + i * 256;
            int r = u >> 4, c4 = u & 15;
            float4 v = *(const float4*)(W + (size_t)r * 256 + k0 + c4 * 4);
            short* dst = &Bs[r][c4 * 4];
            dst[0] = f2bf(v.x); dst[1] = f2bf(v.y); dst[2] = f2bf(v.z); dst[3] = f2bf(v.w);
        }
        __syncthreads();
        #pragma unroll
        for (int kl = 0; kl < 2; ++kl) {
            bf16x8 a[2];
            #pragma unroll
            for (int m = 0; m < 2; ++m)
                a[m] = *(const bf16x8*)&As[wave * 32 + m * 16 + lo][kl * 32 + hi * 8];
            #pragma unroll
            for (int n = 0; n < 16; ++n) {
                bf16x8 b = *(const bf16x8*)&Bs[n * 16 + lo][kl * 32 + hi * 8];
                #pragma unroll
                for (int m = 0; m < 2; ++m)
                    acc[m][n] = __builtin_amdgcn_mfma_f32_16x16x32_bf16(a[m], b, acc[m][n], 0, 0, 0);
            }
        }
    }

    // epilogue: C-frag row = (lane>>4)*4 + j, col = lane&15  (m89/m91-verified)
    #pragma unroll
    for (int m = 0; m < 2; ++m)
        #pragma unroll
        for (int n = 0; n < 16; ++n)
            #pragma unroll
            for (int j = 0; j < 4; ++j) {
                int srow = row0 + wave * 32 + m * 16 + hi * 4 + j;
                int e = n * 16 + lo;
                float v = acc[m][n][j];
                if (proj == 0) {
                    q_out[(size_t)srow * 256 + e] = f2bf(v * 0.0625f);  // fold 1/sqrt(256)
                } else if (proj == 1) {
                    k_out[(size_t)srow * 256 + e] = f2bf(v);
                } else {
                    int b = srow >> 12, s = srow & 4095;
                    vt_out[((size_t)b * 256 + e) * 4096 + s] = f2bf(v);
                }
            }
}

// ---------------------------------------------------------------------------
// Flash attention, split-KV x2. grid (32, 4, 2), block 256 (4 waves x 32 q-rows).
// KVBLK = 64. K/V single-buffered LDS, P via per-wave LDS transpose,
// defer-max (THR=8), L via ones-column MFMA.
// ---------------------------------------------------------------------------
__global__ void attn_kernel(const short* __restrict__ qs,   // [16384][256] prescaled
                            const short* __restrict__ kk_,  // [16384][256]
                            const short* __restrict__ vt,   // [4][256][4096]
                            const int*   __restrict__ mask, // [4][4096][4096]
                            float* __restrict__ Opart,      // [2][16384][256]
                            float* __restrict__ Mpart,      // [2][16384]
                            float* __restrict__ Lpart)      // [2][16384]
{
    __shared__ short Ks[64][264];      // 528B rows (16B-aligned, bank-spread)
    __shared__ short Vs[256][72];      // 144B rows
    __shared__ short Ps[4][32][72];    // per-wave P transpose buffer

    const int tid = threadIdx.x;
    const int wave = tid >> 6, lane = tid & 63, lo = lane & 15, hi = lane >> 4;
    const int qt = blockIdx.x, b = blockIdx.y, split = blockIdx.z;
    const int qrow0 = qt * 128 + wave * 32;           // q row base within batch
    const size_t qg0 = (size_t)b * 4096 + qrow0;      // global q row base
    const int kv0 = split * 2048;

    // resident Q fragments: A-frag row = lane&15, k = (lane>>4)*8..+8
    bf16x8 qf[2][8];
    #pragma unroll
    for (int m = 0; m < 2; ++m)
        #pragma unroll
        for (int kk = 0; kk < 8; ++kk)
            qf[m][kk] = *(const bf16x8*)(qs + (qg0 + m * 16 + lo) * 256 + kk * 32 + hi * 8);

    f32x4 oacc[2][16];
    #pragma unroll
    for (int m = 0; m < 2; ++m)
        #pragma unroll
        for (int n = 0; n < 16; ++n) {
            f32x4 z = {0.f, 0.f, 0.f, 0.f};
            oacc[m][n] = z;
        }
    float Mst[2][4], Lst[2][4];
    #pragma unroll
    for (int m = 0; m < 2; ++m)
        #pragma unroll
        for (int j = 0; j < 4; ++j) { Mst[m][j] = -1e30f; Lst[m][j] = 0.f; }

    bf16x8 onesf;
    #pragma unroll
    for (int i = 0; i < 8; ++i) onesf[i] = (short)0x3F80;   // bf16 1.0

    const short* ksrc0 = kk_ + ((size_t)b * 4096 + kv0) * 256;
    const size_t vbase = (size_t)b * 256 * 4096;
    const int* mbase = mask + (size_t)b * 4096 * 4096;

    for (int t = 0; t < 32; ++t) {
        __syncthreads();   // prior iteration done reading Ks/Vs
        // --- stage K tile (64x256, contiguous 32KB) ---
        {
            const short* src = ksrc0 + (size_t)t * 64 * 256;
            #pragma unroll
            for (int i = 0; i < 8; ++i) {
                int u = tid + i * 256;
                bf16x8 v = *(const bf16x8*)(src + u * 8);
                *(bf16x8*)&Ks[u >> 5][(u & 31) * 8] = v;
            }
        }
        // --- stage V^T tile (256 x 64): 2048 bf16x8 units ---
        {
            const int c0 = kv0 + t * 64;
            #pragma unroll
            for (int i = 0; i < 8; ++i) {
                int u = tid + i * 256;
                int r = u >> 3, cu = u & 7;
                bf16x8 v = *(const bf16x8*)(vt + vbase + (size_t)r * 4096 + c0 + cu * 8);
                *(bf16x8*)&Vs[r][cu * 8] = v;
            }
        }
        __syncthreads();

        // --- mask loads (issued early, consumed after QK) ---
        int mrg[2][4][4];
        #pragma unroll
        for (int m = 0; m < 2; ++m)
            #pragma unroll
            for (int n = 0; n < 4; ++n)
                #pragma unroll
                for (int j = 0; j < 4; ++j)
                    mrg[m][n][j] = mbase[(size_t)(qrow0 + m * 16 + hi * 4 + j) * 4096
                                         + kv0 + t * 64 + n * 16 + lo];

        // --- QK^T: S[32q][64k] ---
        f32x4 sacc[2][4];
        #pragma unroll
        for (int m = 0; m < 2; ++m)
            #pragma unroll
            for (int n = 0; n < 4; ++n) {
                f32x4 z = {0.f, 0.f, 0.f, 0.f};
                sacc[m][n] = z;
            }
        #pragma unroll
        for (int kk = 0; kk < 8; ++kk) {
            #pragma unroll
            for (int n = 0; n < 4; ++n) {
                bf16x8 bk = *(const bf16x8*)&Ks[n * 16 + lo][kk * 32 + hi * 8];
                #pragma unroll
                for (int m = 0; m < 2; ++m)
                    sacc[m][n] = __builtin_amdgcn_mfma_f32_16x16x32_bf16(qf[m][kk], bk, sacc[m][n], 0, 0, 0);
            }
        }

        // --- row max (masked), butterfly over the 16-lane column group ---
        float ml[2][4];
        #pragma unroll
        for (int m = 0; m < 2; ++m)
            #pragma unroll
            for (int j = 0; j < 4; ++j) {
                float mx = -1e30f;
                #pragma unroll
                for (int n = 0; n < 4; ++n) {
                    float s = sacc[m][n][j];
                    if (mrg[m][n][j]) s = -1e30f;
                    mx = fmaxf(mx, s);
                }
                #pragma unroll
                for (int d = 1; d < 16; d <<= 1)
                    mx = fmaxf(mx, __shfl_xor(mx, d));
                ml[m][j] = mx;
            }

        // --- defer-max rescale (THR = 8) ---
        bool needl = false;
        #pragma unroll
        for (int m = 0; m < 2; ++m)
            #pragma unroll
            for (int j = 0; j < 4; ++j)
                needl = needl || (ml[m][j] > Mst[m][j] + 8.0f);
        if (__any((int)needl)) {
            #pragma unroll
            for (int m = 0; m < 2; ++m)
                #pragma unroll
                for (int j = 0; j < 4; ++j) {
                    float Mn = fmaxf(Mst[m][j], ml[m][j]);
                    float sc = __expf(Mst[m][j] - Mn);
                    Mst[m][j] = Mn;
                    Lst[m][j] *= sc;
                    #pragma unroll
                    for (int n = 0; n < 16; ++n) oacc[m][n][j] *= sc;
                }
        }

        // --- P = exp(s - M) (masked -> 0), write to per-wave LDS transpose buf ---
        #pragma unroll
        for (int m = 0; m < 2; ++m)
            #pragma unroll
            for (int n = 0; n < 4; ++n)
                #pragma unroll
                for (int j = 0; j < 4; ++j) {
                    float p = __expf(sacc[m][n][j] - Mst[m][j]);
                    if (mrg[m][n][j]) p = 0.0f;
                    Ps[wave][m * 16 + hi * 4 + j][n * 16 + lo] = f2bf(p);
                }

        // --- PV: O[32q][256d] += P[32][64] * V[64][256]; L via ones-column MFMA ---
        f32x4 lacc[2];
        {
            f32x4 z = {0.f, 0.f, 0.f, 0.f};
            lacc[0] = z; lacc[1] = z;
        }
        #pragma unroll
        for (int g = 0; g < 2; ++g) {
            bf16x8 a2[2];
            #pragma unroll
            for (int m = 0; m < 2; ++m)
                a2[m] = *(const bf16x8*)&Ps[wave][m * 16 + lo][g * 32 + hi * 8];
            #pragma unroll
            for (int n = 0; n < 16; ++n) {
                bf16x8 bv = *(const bf16x8*)&Vs[n * 16 + lo][g * 32 + hi * 8];
                #pragma unroll
                for (int m = 0; m < 2; ++m)
                    oacc[m][n] = __builtin_amdgcn_mfma_f32_16x16x32_bf16(a2[m], bv, oacc[m][n], 0, 0, 0);
            }
            #pragma unroll
            for (int m = 0; m < 2; ++m)
                lacc[m] = __builtin_amdgcn_mfma_f32_16x16x32_bf16(a2[m], onesf, lacc[m], 0, 0, 0);
        }
        #pragma unroll
        for (int m = 0; m < 2; ++m)
            #pragma unroll
            for (int j = 0; j < 4; ++j)
                Lst[m][j] += lacc[m][j];
    }

    // --- epilogue: raw partials ---
    const size_t obase = ((size_t)split * 16384 + qg0) * 256;
    #pragma unroll
    for (int m = 0; m < 2; ++m)
        #pragma unroll
        for (int n = 0; n < 16; ++n)
            #pragma unroll
            for (int j = 0; j < 4; ++j)
                Opart[obase + (size_t)(m * 16 + hi * 4 + j) * 256 + n * 16 + lo] = oacc[m][n][j];
    if (lo == 0) {
        #pragma unroll
        for (int m = 0; m < 2; ++m)
            #pragma unroll
            for (int j = 0; j < 4; ++j) {
                size_t r = (size_t)split * 16384 + qg0 + m * 16 + hi * 4 + j;
                Mpart[r] = Mst[m][j];
                Lpart[r] = Lst[m][j];
            }
    }
}

// ---------------------------------------------------------------------------
// Combine the two KV-split partials.  grid 4096, block 256, float4/thread.
// ---------------------------------------------------------------------------
__global__ void combine_kernel(const float* __restrict__ Opart,
                               const float* __restrict__ Mpart,
                               const float* __restrict__ Lpart,
                               float* __restrict__ out)
{
    int gid = blockIdx.x * 256 + threadIdx.x;   // 1,048,576 threads
    int row = gid >> 6, c4 = gid & 63;
    float M0 = Mpart[row], M1 = Mpart[16384 + row];
    float L0 = Lpart[row], L1 = Lpart[16384 + row];
    float M = fmaxf(M0, M1);
    float w0 = __expf(M0 - M), w1 = __expf(M1 - M);
    float inv = 1.0f / (w0 * L0 + w1 * L1);
    float4 o0 = *(const float4*)(Opart + (size_t)row * 256 + c4 * 4);
    float4 o1 = *(const float4*)(Opart + (size_t)16384 * 256 + (size_t)row * 256 + c4 * 4);
    float4 r;
    r.x = (o0.x * w0 + o1.x * w1) * inv;
    r.y = (o0.y * w0 + o1.y * w1) * inv;
    r.z = (o0.z * w0 + o1.z * w1) * inv;
    r.w = (o0.w * w0 + o1.w * w1) * inv;
    *(float4*)(out + (size_t)row * 256 + c4 * 4) = r;
}

// ---------------------------------------------------------------------------
extern "C" void kernel_launch(void* const* d_in, const int* in_sizes, int n_in,
                              void* d_out, int out_size, void* d_ws, size_t ws_size,
                              hipStream_t stream)
{
    const float* encq = (const float*)d_in[0];
    const float* enck = (const float*)d_in[1];
    const float* encv = (const float*)d_in[2];
    const int*   mask = (const int*)d_in[3];
    const float* Wq   = (const float*)d_in[4];
    const float* Wk   = (const float*)d_in[5];
    const float* Wv   = (const float*)d_in[6];

    char* ws = (char*)d_ws;
    short* q_ws  = (short*)(ws);                  //  8 MB  [16384][256] bf16
    short* k_ws  = (short*)(ws + 8388608);        //  8 MB
    short* vt_ws = (short*)(ws + 16777216);       //  8 MB  [4][256][4096] bf16
    float* Opart = (float*)(ws + 25165824);       // 32 MB  [2][16384][256] f32
    float* Mpart = (float*)(ws + 58720256);       // 128 KB
    float* Lpart = (float*)(ws + 58851328);       // 128 KB  (total ~56.3 MB)
    float* out   = (float*)d_out;

    hipLaunchKernelGGL(proj_kernel, dim3(128, 3), dim3(256), 0, stream,
                       encq, enck, encv, Wq, Wk, Wv, q_ws, k_ws, vt_ws);
    hipLaunchKernelGGL(attn_kernel, dim3(32, 4, 2), dim3(256), 0, stream,
                       q_ws, k_ws, vt_ws, mask, Opart, Mpart, Lpart);
    hipLaunchKernelGGL(combine_kernel, dim3(4096), dim3(256), 0, stream,
                       Opart, Mpart, Lpart, out);
}

// Round 3
// 317.314 us; speedup vs baseline: 3.8049x; 3.8049x over previous
//
#include <hip/hip_runtime.h>
#include <hip/hip_bf16.h>
#include <stdint.h>

// Attention_5265629905090: B=4, S=4096, D=256, fp32 in/out, int mask (1 = masked -> -1e9)
// R3: add __launch_bounds__(256,1) — R2 counters showed VGPR capped at 64 with ~1.8GB
// scratch-spill writes per dispatch (WRITE_SIZE 1.82GB vs 33MB legit). Spills gone.

typedef __attribute__((ext_vector_type(8))) short bf16x8;
typedef __attribute__((ext_vector_type(4))) float f32x4;

__device__ __forceinline__ short f2bf(float f) {
    union { float f; uint32_t u; } v; v.f = f;
    uint32_t r = v.u + 0x7FFFu + ((v.u >> 16) & 1u);   // RNE
    return (short)(r >> 16);
}

// ---------------------------------------------------------------------------
// Projection GEMM: C[s][e] = sum_d X[s][d] * W[e][d]   (nn.Linear, y = x W^T)
// grid (128, 3), block 256.  proj: 0=Q (scaled 1/16), 1=K, 2=V^T
// ---------------------------------------------------------------------------
__global__ __launch_bounds__(256, 1)
void proj_kernel(const float* __restrict__ encq,
                 const float* __restrict__ enck,
                 const float* __restrict__ encv,
                 const float* __restrict__ Wq,
                 const float* __restrict__ Wk,
                 const float* __restrict__ Wv,
                 short* __restrict__ q_out,   // [16384][256]
                 short* __restrict__ k_out,   // [16384][256]
                 short* __restrict__ vt_out)  // [4][256][4096]
{
    __shared__ short As[128][72];   // 72-short rows: 144B = 16B-aligned, bank-spread
    __shared__ short Bs[256][72];

    const int tid = threadIdx.x;
    const int wave = tid >> 6, lane = tid & 63, lo = lane & 15, hi = lane >> 4;
    const int proj = blockIdx.y;
    const int row0 = blockIdx.x * 128;

    const float* X = (proj == 0) ? encq : (proj == 1) ? enck : encv;
    const float* W = (proj == 0) ? Wq   : (proj == 1) ? Wk   : Wv;

    f32x4 acc[2][16];
    #pragma unroll
    for (int m = 0; m < 2; ++m)
        #pragma unroll
        for (int n = 0; n < 16; ++n) {
            f32x4 z = {0.f, 0.f, 0.f, 0.f};
            acc[m][n] = z;
        }

    for (int ks = 0; ks < 4; ++ks) {
        const int k0 = ks * 64;
        __syncthreads();
        // stage A tile: 128 rows x 64 cols fp32 -> bf16
        #pragma unroll
        for (int i = 0; i < 8; ++i) {
            int u = tid + i * 256;
            int r = u >> 4, c4 = u & 15;
            float4 v = *(const float4*)(X + (size_t)(row0 + r) * 256 + k0 + c4 * 4);
            short* dst = &As[r][c4 * 4];
            dst[0] = f2bf(v.x); dst[1] = f2bf(v.y); dst[2] = f2bf(v.z); dst[3] = f2bf(v.w);
        }
        // stage W tile: 256 rows x 64 cols
        #pragma unroll
        for (int i = 0; i < 16; ++i) {
            int u = tid + i * 256;
            int r = u >> 4, c4 = u & 15;
            float4 v = *(const float4*)(W + (size_t)r * 256 + k0 + c4 * 4);
            short* dst = &Bs[r][c4 * 4];
            dst[0] = f2bf(v.x); dst[1] = f2bf(v.y); dst[2] = f2bf(v.z); dst[3] = f2bf(v.w);
        }
        __syncthreads();
        #pragma unroll
        for (int kl = 0; kl < 2; ++kl) {
            bf16x8 a[2];
            #pragma unroll
            for (int m = 0; m < 2; ++m)
                a[m] = *(const bf16x8*)&As[wave * 32 + m * 16 + lo][kl * 32 + hi * 8];
            #pragma unroll
            for (int n = 0; n < 16; ++n) {
                bf16x8 b = *(const bf16x8*)&Bs[n * 16 + lo][kl * 32 + hi * 8];
                #pragma unroll
                for (int m = 0; m < 2; ++m)
                    acc[m][n] = __builtin_amdgcn_mfma_f32_16x16x32_bf16(a[m], b, acc[m][n], 0, 0, 0);
            }
        }
    }

    // epilogue: C-frag row = (lane>>4)*4 + j, col = lane&15  (m89/m91-verified)
    #pragma unroll
    for (int m = 0; m < 2; ++m)
        #pragma unroll
        for (int n = 0; n < 16; ++n)
            #pragma unroll
            for (int j = 0; j < 4; ++j) {
                int srow = row0 + wave * 32 + m * 16 + hi * 4 + j;
                int e = n * 16 + lo;
                float v = acc[m][n][j];
                if (proj == 0) {
                    q_out[(size_t)srow * 256 + e] = f2bf(v * 0.0625f);  // fold 1/sqrt(256)
                } else if (proj == 1) {
                    k_out[(size_t)srow * 256 + e] = f2bf(v);
                } else {
                    int b = srow >> 12, s = srow & 4095;
                    vt_out[((size_t)b * 256 + e) * 4096 + s] = f2bf(v);
                }
            }
}

// ---------------------------------------------------------------------------
// Flash attention, split-KV x2. grid (32, 4, 2), block 256 (4 waves x 32 q-rows).
// KVBLK = 64. K/V single-buffered LDS, P via per-wave LDS transpose,
// defer-max (THR=8), L via ones-column MFMA.
// ---------------------------------------------------------------------------
__global__ __launch_bounds__(256, 1)
void attn_kernel(const short* __restrict__ qs,   // [16384][256] prescaled
                 const short* __restrict__ kk_,  // [16384][256]
                 const short* __restrict__ vt,   // [4][256][4096]
                 const int*   __restrict__ mask, // [4][4096][4096]
                 float* __restrict__ Opart,      // [2][16384][256]
                 float* __restrict__ Mpart,      // [2][16384]
                 float* __restrict__ Lpart)      // [2][16384]
{
    __shared__ short Ks[64][264];      // 528B rows (16B-aligned, bank-spread)
    __shared__ short Vs[256][72];      // 144B rows
    __shared__ short Ps[4][32][72];    // per-wave P transpose buffer

    const int tid = threadIdx.x;
    const int wave = tid >> 6, lane = tid & 63, lo = lane & 15, hi = lane >> 4;
    const int qt = blockIdx.x, b = blockIdx.y, split = blockIdx.z;
    const int qrow0 = qt * 128 + wave * 32;           // q row base within batch
    const size_t qg0 = (size_t)b * 4096 + qrow0;      // global q row base
    const int kv0 = split * 2048;

    // resident Q fragments: A-frag row = lane&15, k = (lane>>4)*8..+8
    bf16x8 qf[2][8];
    #pragma unroll
    for (int m = 0; m < 2; ++m)
        #pragma unroll
        for (int kk = 0; kk < 8; ++kk)
            qf[m][kk] = *(const bf16x8*)(qs + (qg0 + m * 16 + lo) * 256 + kk * 32 + hi * 8);

    f32x4 oacc[2][16];
    #pragma unroll
    for (int m = 0; m < 2; ++m)
        #pragma unroll
        for (int n = 0; n < 16; ++n) {
            f32x4 z = {0.f, 0.f, 0.f, 0.f};
            oacc[m][n] = z;
        }
    float Mst[2][4], Lst[2][4];
    #pragma unroll
    for (int m = 0; m < 2; ++m)
        #pragma unroll
        for (int j = 0; j < 4; ++j) { Mst[m][j] = -1e30f; Lst[m][j] = 0.f; }

    bf16x8 onesf;
    #pragma unroll
    for (int i = 0; i < 8; ++i) onesf[i] = (short)0x3F80;   // bf16 1.0

    const short* ksrc0 = kk_ + ((size_t)b * 4096 + kv0) * 256;
    const size_t vbase = (size_t)b * 256 * 4096;
    const int* mbase = mask + (size_t)b * 4096 * 4096;

    for (int t = 0; t < 32; ++t) {
        __syncthreads();   // prior iteration done reading Ks/Vs
        // --- stage K tile (64x256, contiguous 32KB) ---
        {
            const short* src = ksrc0 + (size_t)t * 64 * 256;
            #pragma unroll
            for (int i = 0; i < 8; ++i) {
                int u = tid + i * 256;
                bf16x8 v = *(const bf16x8*)(src + u * 8);
                *(bf16x8*)&Ks[u >> 5][(u & 31) * 8] = v;
            }
        }
        // --- stage V^T tile (256 x 64): 2048 bf16x8 units ---
        {
            const int c0 = kv0 + t * 64;
            #pragma unroll
            for (int i = 0; i < 8; ++i) {
                int u = tid + i * 256;
                int r = u >> 3, cu = u & 7;
                bf16x8 v = *(const bf16x8*)(vt + vbase + (size_t)r * 4096 + c0 + cu * 8);
                *(bf16x8*)&Vs[r][cu * 8] = v;
            }
        }
        __syncthreads();

        // --- mask loads (issued early, consumed after QK) ---
        int mrg[2][4][4];
        #pragma unroll
        for (int m = 0; m < 2; ++m)
            #pragma unroll
            for (int n = 0; n < 4; ++n)
                #pragma unroll
                for (int j = 0; j < 4; ++j)
                    mrg[m][n][j] = mbase[(size_t)(qrow0 + m * 16 + hi * 4 + j) * 4096
                                         + kv0 + t * 64 + n * 16 + lo];

        // --- QK^T: S[32q][64k] ---
        f32x4 sacc[2][4];
        #pragma unroll
        for (int m = 0; m < 2; ++m)
            #pragma unroll
            for (int n = 0; n < 4; ++n) {
                f32x4 z = {0.f, 0.f, 0.f, 0.f};
                sacc[m][n] = z;
            }
        #pragma unroll
        for (int kk = 0; kk < 8; ++kk) {
            #pragma unroll
            for (int n = 0; n < 4; ++n) {
                bf16x8 bk = *(const bf16x8*)&Ks[n * 16 + lo][kk * 32 + hi * 8];
                #pragma unroll
                for (int m = 0; m < 2; ++m)
                    sacc[m][n] = __builtin_amdgcn_mfma_f32_16x16x32_bf16(qf[m][kk], bk, sacc[m][n], 0, 0, 0);
            }
        }

        // --- row max (masked), butterfly over the 16-lane column group ---
        float ml[2][4];
        #pragma unroll
        for (int m = 0; m < 2; ++m)
            #pragma unroll
            for (int j = 0; j < 4; ++j) {
                float mx = -1e30f;
                #pragma unroll
                for (int n = 0; n < 4; ++n) {
                    float s = sacc[m][n][j];
                    if (mrg[m][n][j]) s = -1e30f;
                    mx = fmaxf(mx, s);
                }
                #pragma unroll
                for (int d = 1; d < 16; d <<= 1)
                    mx = fmaxf(mx, __shfl_xor(mx, d));
                ml[m][j] = mx;
            }

        // --- defer-max rescale (THR = 8) ---
        bool needl = false;
        #pragma unroll
        for (int m = 0; m < 2; ++m)
            #pragma unroll
            for (int j = 0; j < 4; ++j)
                needl = needl || (ml[m][j] > Mst[m][j] + 8.0f);
        if (__any((int)needl)) {
            #pragma unroll
            for (int m = 0; m < 2; ++m)
                #pragma unroll
                for (int j = 0; j < 4; ++j) {
                    float Mn = fmaxf(Mst[m][j], ml[m][j]);
                    float sc = __expf(Mst[m][j] - Mn);
                    Mst[m][j] = Mn;
                    Lst[m][j] *= sc;
                    #pragma unroll
                    for (int n = 0; n < 16; ++n) oacc[m][n][j] *= sc;
                }
        }

        // --- P = exp(s - M) (masked -> 0), write to per-wave LDS transpose buf ---
        #pragma unroll
        for (int m = 0; m < 2; ++m)
            #pragma unroll
            for (int n = 0; n < 4; ++n)
                #pragma unroll
                for (int j = 0; j < 4; ++j) {
                    float p = __expf(sacc[m][n][j] - Mst[m][j]);
                    if (mrg[m][n][j]) p = 0.0f;
                    Ps[wave][m * 16 + hi * 4 + j][n * 16 + lo] = f2bf(p);
                }

        // --- PV: O[32q][256d] += P[32][64] * V[64][256]; L via ones-column MFMA ---
        f32x4 lacc[2];
        {
            f32x4 z = {0.f, 0.f, 0.f, 0.f};
            lacc[0] = z; lacc[1] = z;
        }
        #pragma unroll
        for (int g = 0; g < 2; ++g) {
            bf16x8 a2[2];
            #pragma unroll
            for (int m = 0; m < 2; ++m)
                a2[m] = *(const bf16x8*)&Ps[wave][m * 16 + lo][g * 32 + hi * 8];
            #pragma unroll
            for (int n = 0; n < 16; ++n) {
                bf16x8 bv = *(const bf16x8*)&Vs[n * 16 + lo][g * 32 + hi * 8];
                #pragma unroll
                for (int m = 0; m < 2; ++m)
                    oacc[m][n] = __builtin_amdgcn_mfma_f32_16x16x32_bf16(a2[m], bv, oacc[m][n], 0, 0, 0);
            }
            #pragma unroll
            for (int m = 0; m < 2; ++m)
                lacc[m] = __builtin_amdgcn_mfma_f32_16x16x32_bf16(a2[m], onesf, lacc[m], 0, 0, 0);
        }
        #pragma unroll
        for (int m = 0; m < 2; ++m)
            #pragma unroll
            for (int j = 0; j < 4; ++j)
                Lst[m][j] += lacc[m][j];
    }

    // --- epilogue: raw partials ---
    const size_t obase = ((size_t)split * 16384 + qg0) * 256;
    #pragma unroll
    for (int m = 0; m < 2; ++m)
        #pragma unroll
        for (int n = 0; n < 16; ++n)
            #pragma unroll
            for (int j = 0; j < 4; ++j)
                Opart[obase + (size_t)(m * 16 + hi * 4 + j) * 256 + n * 16 + lo] = oacc[m][n][j];
    if (lo == 0) {
        #pragma unroll
        for (int m = 0; m < 2; ++m)
            #pragma unroll
            for (int j = 0; j < 4; ++j) {
                size_t r = (size_t)split * 16384 + qg0 + m * 16 + hi * 4 + j;
                Mpart[r] = Mst[m][j];
                Lpart[r] = Lst[m][j];
            }
    }
}

// ---------------------------------------------------------------------------
// Combine the two KV-split partials.  grid 4096, block 256, float4/thread.
// ---------------------------------------------------------------------------
__global__ __launch_bounds__(256)
void combine_kernel(const float* __restrict__ Opart,
                    const float* __restrict__ Mpart,
                    const float* __restrict__ Lpart,
                    float* __restrict__ out)
{
    int gid = blockIdx.x * 256 + threadIdx.x;   // 1,048,576 threads
    int row = gid >> 6, c4 = gid & 63;
    float M0 = Mpart[row], M1 = Mpart[16384 + row];
    float L0 = Lpart[row], L1 = Lpart[16384 + row];
    float M = fmaxf(M0, M1);
    float w0 = __expf(M0 - M), w1 = __expf(M1 - M);
    float inv = 1.0f / (w0 * L0 + w1 * L1);
    float4 o0 = *(const float4*)(Opart + (size_t)row * 256 + c4 * 4);
    float4 o1 = *(const float4*)(Opart + (size_t)16384 * 256 + (size_t)row * 256 + c4 * 4);
    float4 r;
    r.x = (o0.x * w0 + o1.x * w1) * inv;
    r.y = (o0.y * w0 + o1.y * w1) * inv;
    r.z = (o0.z * w0 + o1.z * w1) * inv;
    r.w = (o0.w * w0 + o1.w * w1) * inv;
    *(float4*)(out + (size_t)row * 256 + c4 * 4) = r;
}

// ---------------------------------------------------------------------------
extern "C" void kernel_launch(void* const* d_in, const int* in_sizes, int n_in,
                              void* d_out, int out_size, void* d_ws, size_t ws_size,
                              hipStream_t stream)
{
    const float* encq = (const float*)d_in[0];
    const float* enck = (const float*)d_in[1];
    const float* encv = (const float*)d_in[2];
    const int*   mask = (const int*)d_in[3];
    const float* Wq   = (const float*)d_in[4];
    const float* Wk   = (const float*)d_in[5];
    const float* Wv   = (const float*)d_in[6];

    char* ws = (char*)d_ws;
    short* q_ws  = (short*)(ws);                  //  8 MB  [16384][256] bf16
    short* k_ws  = (short*)(ws + 8388608);        //  8 MB
    short* vt_ws = (short*)(ws + 16777216);       //  8 MB  [4][256][4096] bf16
    float* Opart = (float*)(ws + 25165824);       // 32 MB  [2][16384][256] f32
    float* Mpart = (float*)(ws + 58720256);       // 128 KB
    float* Lpart = (float*)(ws + 58851328);       // 128 KB  (total ~56.3 MB)
    float* out   = (float*)d_out;

    hipLaunchKernelGGL(proj_kernel, dim3(128, 3), dim3(256), 0, stream,
                       encq, enck, encv, Wq, Wk, Wv, q_ws, k_ws, vt_ws);
    hipLaunchKernelGGL(attn_kernel, dim3(32, 4, 2), dim3(256), 0, stream,
                       q_ws, k_ws, vt_ws, mask, Opart, Mpart, Lpart);
    hipLaunchKernelGGL(combine_kernel, dim3(4096), dim3(256), 0, stream,
                       Opart, Mpart, Lpart, out);
}